// Round 7
// baseline (867.011 us; speedup 1.0000x reference)
//
#include <hip/hip_runtime.h>
#include <hip/hip_cooperative_groups.h>
#include <math.h>

namespace cg = cooperative_groups;

// Problem constants
#define BB 16
#define NN 1024
#define DD 512
#define KK 8
#define EPS_ 1e-8f
#define LN_EPS_ 1e-5f
// -0.5 * D * log(2*pi)
#define GLL_C0 (-470.4965290007924f)

typedef __attribute__((ext_vector_type(8))) short short8;
typedef __attribute__((ext_vector_type(4))) short short4v;
typedef __attribute__((ext_vector_type(4))) float f32x4;

static __device__ inline short f2bf(float f) {
    unsigned u = __builtin_bit_cast(unsigned, f);
    u = (u + 0x7fff + ((u >> 16) & 1)) >> 16;
    return (short)u;
}
static __device__ inline float bf2f(short s) {
    unsigned u = ((unsigned)(unsigned short)s) << 16;
    return __builtin_bit_cast(float, u);
}
static __device__ inline void gload16(const void* g, void* l) {
    __builtin_amdgcn_global_load_lds(
        (const __attribute__((address_space(1))) void*)g,
        (__attribute__((address_space(3))) void*)l, 16, 0, 0);
}

struct Params {
    const float *emb, *noise_init, *noise_final, *slots_mu, *slots_logsg,
                *mixing_co, *Wk, *bk, *Wq, *bq, *Wv, *bv, *ln_g, *ln_b;
    float *out;
    float *queries, *attn, *s1p, *s2p, *off, *mix16, *colsum;
    short *Abf, *E, *Vbf, *WtKV, *WqT, *slotbf, *F_bt;
};

// ===========================================================================
// Phase bodies (shared between the fused cooperative kernel and the
// standalone fallback kernels).
// ===========================================================================

// ---- pre: u in [0,4992) : LN+cast | weight transpose | slot init ----------
static __device__ __forceinline__ void do_pre(const Params& p, int u, int tid,
                                              short* eb)
{
    if (u < 4096) {
        int row  = u * 4 + (tid >> 6);
        int lane = tid & 63;
        const float* e = p.emb + (size_t)row * DD + lane * 8;
        float4 v0 = *(const float4*)e;
        float4 v1 = *(const float4*)(e + 4);
        float v[8] = {v0.x, v0.y, v0.z, v0.w, v1.x, v1.y, v1.z, v1.w};
        float s = 0.0f;
#pragma unroll
        for (int j = 0; j < 8; j++) s += v[j];
#pragma unroll
        for (int off = 32; off; off >>= 1) s += __shfl_xor(s, off);
        float m = s * (1.0f / DD);
        float vs = 0.0f;
#pragma unroll
        for (int j = 0; j < 8; j++) { float d = v[j] - m; vs = fmaf(d, d, vs); }
#pragma unroll
        for (int off = 32; off; off >>= 1) vs += __shfl_xor(vs, off);
        float rstd = rsqrtf(vs * (1.0f / DD) + LN_EPS_);

        float4 g0 = *(const float4*)&p.ln_g[lane * 8];
        float4 g1 = *(const float4*)&p.ln_g[lane * 8 + 4];
        float4 b0 = *(const float4*)&p.ln_b[lane * 8];
        float4 b1 = *(const float4*)&p.ln_b[lane * 8 + 4];
        float g[8] = {g0.x, g0.y, g0.z, g0.w, g1.x, g1.y, g1.z, g1.w};
        float bb[8] = {b0.x, b0.y, b0.z, b0.w, b1.x, b1.y, b1.z, b1.w};
        short8 o;
#pragma unroll
        for (int j = 0; j < 8; j++) o[j] = f2bf(fmaf((v[j] - m) * rstd, g[j], bb[j]));
        *(short8*)&p.Abf[(size_t)row * DD + lane * 8] = o;
    } else if (u < 4864) {
        int idx = u - 4096;
        int z = idx >> 8, rem = idx & 255;
        const float* W = (z == 0) ? p.Wk : (z == 1) ? p.Wv : p.Wq;
        short* T; int nbase;
        if (z < 2) { T = p.WtKV; nbase = z * 512; } else { T = p.WqT; nbase = 0; }
        int k0 = (rem & 15) * 32, n0 = (rem >> 4) * 32;
        int tx = tid & 31, ty = tid >> 5;
        float (*t)[33] = (float (*)[33])eb;
        __syncthreads();
#pragma unroll
        for (int q = 0; q < 4; q++)
            t[ty + q * 8][tx] = W[(size_t)(k0 + ty + q * 8) * DD + n0 + tx];
        __syncthreads();
#pragma unroll
        for (int q = 0; q < 4; q++)
            T[(size_t)(nbase + n0 + ty + q * 8) * DD + k0 + tx] = f2bf(t[tx][ty + q * 8]);
        __syncthreads();
    } else {
        int idx = u - 4864;
        int b = idx >> 3, k = idx & 7;
#pragma unroll
        for (int q = 0; q < 2; q++) {
            int d = tid + q * 256;
            float sg = expf(p.slots_logsg[k * DD + d]);
            float sl = fmaf(sg, p.noise_init[((size_t)(b * KK + k)) * DD + d],
                            p.slots_mu[k * DD + d]);
            p.slotbf[((size_t)(b * KK + k)) * DD + d] = f2bf(sl);
        }
    }
}

// ---- gemm: u in [0,1032) : 128x128 tile MFMA GEMM, LDS-coalesced epilogue -
static __device__ __forceinline__ void do_gemm(const Params& p, int u, int tid,
                                               short* eb)
{
    int w = tid >> 6, l = tid & 63;
    int x = u & 7, by = u >> 3;
    int qmode = (by == 128);
    if (qmode && x >= 4) return;
    const short* A  = qmode ? p.slotbf : p.Abf + (size_t)by * 128 * DD;
    const short* Bt = qmode ? p.WqT : p.WtKV;
    int row0 = qmode ? 0 : by * 128;
    int col0 = x * 128;

    short* As = eb;
    short* Bs = eb + 8192;
    int sr = l >> 3;
    int sg_off = ((l & 7) ^ sr) * 8;
    int mq = (w & 1) * 64, nq = (w >> 1) * 64;
    int fr = l & 15;
    int orow = (l >> 4) * 4, ocol = l & 15;

    f32x4 acc[4][4] = {};
    for (int k0 = 0; k0 < DD; k0 += 64) {
        __syncthreads();
#pragma unroll
        for (int j = 0; j < 4; j++) {
            int rb = w * 32 + j * 8;
            int r  = rb + sr;
            gload16(A  + (size_t)r * DD + k0 + sg_off, &As[rb * 64 + l * 8]);
            gload16(Bt + (size_t)(col0 + r) * DD + k0 + sg_off, &Bs[rb * 64 + l * 8]);
        }
        __syncthreads();
#pragma unroll
        for (int kk = 0; kk < 2; kk++) {
            int g = kk * 4 + (l >> 4);
            short8 af[4], bfv[4];
#pragma unroll
            for (int mi = 0; mi < 4; mi++)
                af[mi] = *(const short8*)&As[(mq + mi * 16 + fr) * 64 + (g ^ (fr & 7)) * 8];
#pragma unroll
            for (int ni = 0; ni < 4; ni++)
                bfv[ni] = *(const short8*)&Bs[(nq + ni * 16 + fr) * 64 + (g ^ (fr & 7)) * 8];
#pragma unroll
            for (int mi = 0; mi < 4; mi++)
#pragma unroll
                for (int ni = 0; ni < 4; ni++)
                    acc[mi][ni] = __builtin_amdgcn_mfma_f32_16x16x32_bf16(
                        af[mi], bfv[ni], acc[mi][ni], 0, 0, 0);
        }
    }

    float bvv[4];
#pragma unroll
    for (int ni = 0; ni < 4; ni++) {
        int col = col0 + nq + ni * 16 + ocol;
        bvv[ni] = qmode ? p.bq[col] : (x < 4 ? p.bk[col] : p.bv[col - 512]);
    }

    __syncthreads();
    if (qmode) {
#pragma unroll
        for (int ni = 0; ni < 4; ni++) {
            int col = col0 + nq + ni * 16 + ocol;
#pragma unroll
            for (int mi = 0; mi < 4; mi++)
#pragma unroll
                for (int r = 0; r < 4; r++)
                    p.queries[(size_t)(mq + mi * 16 + orow + r) * DD + col] =
                        acc[mi][ni][r] + bvv[ni];
        }
    } else {
        int npass = (x < 4) ? 2 : 1;
        for (int pass = 0; pass < npass; pass++) {
#pragma unroll
            for (int mi = 0; mi < 4; mi++)
#pragma unroll
                for (int r = 0; r < 4; r++) {
                    int row = mq + mi * 16 + orow + r;
                    int sw = ((row >> 2) & 3) << 1;
#pragma unroll
                    for (int ni = 0; ni < 4; ni++) {
                        int colg = nq + ni * 16 + ocol;
                        float val = acc[mi][ni][r] + bvv[ni];
                        if (x < 4 && pass == 0) val = val * val;
                        eb[row * 128 + (((colg >> 3) ^ sw) * 8) + (colg & 7)] = f2bf(val);
                    }
                }
            __syncthreads();
#pragma unroll
            for (int i = 0; i < 8; i++) {
                int row = i * 16 + w * 4 + (l >> 4);
                int c = l & 15;
                int cc = c ^ (((row >> 2) & 3) << 1);
                short8 vv = *(const short8*)&eb[row * 128 + cc * 8];
                if (x < 4) {
                    size_t a = (size_t)(row0 + row) * 1024 +
                               (pass ? 512 + col0 : col0) + c * 8;
                    *(short8*)&p.E[a] = vv;
                } else {
                    *(short8*)&p.Vbf[(size_t)(row0 + row) * 512 +
                                     (col0 - 512) + c * 8] = vv;
                }
            }
            __syncthreads();
        }
    }
}

// ---- fprep0: u in [0,256) ------------------------------------------------
static __device__ __forceinline__ void do_fprep0(const Params& p, int u, int tid,
                                                 float* red)
{
    int b = u >> 4, k = u & 15;
    short* Fr = p.F_bt + (size_t)(b * 16 + k) * 1024;
    if (k >= KK) {
        short4v zv = {0, 0, 0, 0};
        *(short4v*)&Fr[tid * 4] = zv;
        if (tid == 0) { p.off[b * 16 + k] = 0.0f; p.mix16[b * 16 + k] = 0.0f; }
        return;
    }
    float* rc = red;
    float* rl = red + 256;
    float c = 0.0f, ld = 0.0f;
#pragma unroll
    for (int q = 0; q < 2; q++) {
        int d = tid * 2 + q;
        float sg = expf(p.slots_logsg[k * DD + d]);
        float iv = 1.0f / (sg * sg + EPS_);
        float qv = p.queries[((size_t)(b * KK + k)) * DD + d];
        Fr[d]       = f2bf(-0.5f * iv);
        Fr[512 + d] = f2bf(qv * iv);
        c  = fmaf(qv * qv, iv, c);
        ld += logf(fabsf(sg) + EPS_);
    }
    __syncthreads();
    rc[tid] = c; rl[tid] = ld;
    __syncthreads();
    for (int s = 128; s > 0; s >>= 1) {
        if (tid < s) { rc[tid] += rc[tid + s]; rl[tid] += rl[tid + s]; }
        __syncthreads();
    }
    if (tid == 0) {
        p.off[b * 16 + k]    = GLL_C0 - 0.5f * rl[0] - 0.5f * rc[0];
        p.mix16[b * 16 + k]  = p.mixing_co[k];
        p.colsum[b * KK + k] = 0.0f;
    }
}

// ---- gll: u in [0,1024) --------------------------------------------------
static __device__ __forceinline__ void do_gll(const Params& p, int u, int tid,
                                              short* eb)
{
    int w = tid >> 6, l = tid & 63;
    int b = u >> 6;
    int m0 = (u & 63) * 16;
    const short* Ea = p.E + ((size_t)(b * NN + m0 + (l & 15))) * 1024 + (l >> 4) * 8;
    const short* Fa = p.F_bt + (size_t)(b * 16 + (l & 15)) * 1024 + (l >> 4) * 8;
    f32x4 acc = {};
    int kbase = w * 256;
#pragma unroll
    for (int j = 0; j < 8; j++) {
        int k0 = kbase + j * 32;
        short8 af = *(const short8*)&Ea[k0];
        short8 bf = *(const short8*)&Fa[k0];
        acc = __builtin_amdgcn_mfma_f32_16x16x32_bf16(af, bf, acc, 0, 0, 0);
    }
    f32x4* red = (f32x4*)eb;
    __syncthreads();
    if (w) red[(w - 1) * 64 + l] = acc;
    __syncthreads();
    if (w == 0) {
#pragma unroll
        for (int i = 0; i < 3; i++) acc += red[i * 64 + l];
        int col = l & 15;
        int rbase = m0 + (l >> 4) * 4;
        float offv = p.off[b * 16 + col];
        float mixv = p.mix16[b * 16 + col];
        float a[4], den[4];
#pragma unroll
        for (int r = 0; r < 4; r++) {
            a[r] = mixv * (acc[r] + offv);
            den[r] = a[r];
        }
#pragma unroll
        for (int mask = 1; mask <= 8; mask <<= 1)
#pragma unroll
            for (int r = 0; r < 4; r++) den[r] += __shfl_xor(den[r], mask);
        float csl = 0.0f;
        if (col < KK) {
#pragma unroll
            for (int r = 0; r < 4; r++) {
                float vv = a[r] / den[r];
                p.attn[((size_t)(b * NN + rbase + r)) * KK + col] = vv;
                csl += vv;
            }
        }
        csl += __shfl_xor(csl, 16);
        csl += __shfl_xor(csl, 32);
        if (l < KK) atomicAdd(&p.colsum[b * KK + l], csl);
    }
}

// ---- musigma: u in [0,256) -----------------------------------------------
static __device__ __forceinline__ void do_musigma(const Params& p, int u, int tid,
                                                  float* asml)
{
    int b = u >> 4, ns = u & 15;
    int d0 = tid * 2;
    const float* ab = p.attn + ((size_t)(b * NN + ns * 64)) * KK;
    __syncthreads();
    if (tid < 128) ((float4*)asml)[tid] = ((const float4*)ab)[tid];
    __syncthreads();
    float s1[2][KK] = {}, s2[2][KK] = {};
    const short* vb = p.Vbf + ((size_t)(b * NN + ns * 64)) * DD + d0;
#pragma unroll 4
    for (int nn = 0; nn < 64; nn++) {
        short2 vs = *(const short2*)&vb[(size_t)nn * DD];
        float v0 = bf2f(vs.x), v1 = bf2f(vs.y);
        float v0q = v0 * v0, v1q = v1 * v1;
#pragma unroll
        for (int k = 0; k < KK; k++) {
            float a = asml[nn * KK + k];
            s1[0][k] = fmaf(a, v0, s1[0][k]);
            s2[0][k] = fmaf(a, v0q, s2[0][k]);
            s1[1][k] = fmaf(a, v1, s1[1][k]);
            s2[1][k] = fmaf(a, v1q, s2[1][k]);
        }
    }
    size_t base = ((size_t)(b * 16 + ns) * KK) * DD + d0;
#pragma unroll
    for (int k = 0; k < KK; k++) {
        *(float2*)&p.s1p[base + (size_t)k * DD] = make_float2(s1[0][k], s1[1][k]);
        *(float2*)&p.s2p[base + (size_t)k * DD] = make_float2(s2[0][k], s2[1][k]);
    }
}

// ---- fprep: u in [0,128) -------------------------------------------------
static __device__ __forceinline__ void do_fprep(const Params& p, int u, int tid,
                                                float* red)
{
    int b = u >> 3, k = u & 7;
    float cs   = p.colsum[b * KK + k];
    float inv  = 1.0f / (cs + EPS_);
    float ssum = cs * inv;
    short* Fr = p.F_bt + (size_t)(b * 16 + k) * 1024;
    float* rc = red;
    float* rl = red + 256;
    float c = 0.0f, ld = 0.0f;
#pragma unroll
    for (int q = 0; q < 2; q++) {
        int d = tid * 2 + q;
        float s1 = 0.0f, s2 = 0.0f;
#pragma unroll
        for (int ns = 0; ns < 16; ns++) {
            size_t o = ((size_t)(b * 16 + ns) * KK + k) * DD + d;
            s1 += p.s1p[o];
            s2 += p.s2p[o];
        }
        float m  = s1 * inv;
        float sg = s2 * inv - m * m * (2.0f - ssum);
        float iv = 1.0f / (sg * sg + EPS_);
        float qv = p.queries[((size_t)(b * KK + k)) * DD + d];
        Fr[d]       = f2bf(-0.5f * iv);
        Fr[512 + d] = f2bf(qv * iv);
        c  = fmaf(qv * qv, iv, c);
        ld += logf(fabsf(sg) + EPS_);
    }
    __syncthreads();
    rc[tid] = c; rl[tid] = ld;
    __syncthreads();
    for (int s = 128; s > 0; s >>= 1) {
        if (tid < s) { rc[tid] += rc[tid + s]; rl[tid] += rl[tid + s]; }
        __syncthreads();
    }
    if (tid == 0) {
        p.off[b * 16 + k]    = GLL_C0 - 0.5f * rl[0] - 0.5f * rc[0];
        p.mix16[b * 16 + k]  = ssum * (1.0f / NN);
        p.colsum[b * KK + k] = 0.0f;
    }
}

// ---- final: u in [0,768) -------------------------------------------------
static __device__ __forceinline__ void do_final(const Params& p, int u, int tid)
{
    if (u < 256) {
        int gid = u * 256 + tid;
        int d = gid & 511;
        int k = (gid >> 9) & 7;
        int b = gid >> 12;
        float s1 = 0.0f, s2 = 0.0f;
#pragma unroll
        for (int ns = 0; ns < 16; ns++) {
            size_t o = ((size_t)(b * 16 + ns) * KK + k) * DD + d;
            s1 += p.s1p[o];
            s2 += p.s2p[o];
        }
        float cs   = p.colsum[b * KK + k];
        float inv  = 1.0f / (cs + EPS_);
        float ssum = cs * inv;
        float m    = s1 * inv;
        float sg   = s2 * inv - m * m * (2.0f - ssum);
        p.out[gid] = fmaf(fmaxf(fabsf(sg), EPS_), p.noise_final[gid], m);
    } else {
        int gid = (u - 256) * 256 + tid;
        int b = gid >> 13;
        int k = (gid >> 10) & 7;
        int n = gid & 1023;
        float cs = p.colsum[b * KK + k];
        p.out[BB * KK * DD + gid] =
            p.attn[((size_t)(b * NN + n)) * KK + k] / (cs + EPS_);
    }
}

// ===========================================================================
// Fused cooperative kernel
// ===========================================================================
__global__ __launch_bounds__(256, 2) void fused_kernel(Params p)
{
    cg::grid_group gg = cg::this_grid();
    __shared__ __align__(16) short eb[128 * 128];
    int bid = blockIdx.x, tid = threadIdx.x;
    int G = gridDim.x;

    for (int u = bid; u < 4992; u += G) do_pre(p, u, tid, eb);
    gg.sync();
    for (int u = bid; u < 1032; u += G) do_gemm(p, u, tid, eb);
    gg.sync();
    for (int u = bid; u < 256; u += G) do_fprep0(p, u, tid, (float*)eb);
    gg.sync();
    for (int it = 0; it < 3; it++) {
        for (int u = bid; u < 1024; u += G) do_gll(p, u, tid, eb);
        gg.sync();
        for (int u = bid; u < 256; u += G) do_musigma(p, u, tid, (float*)eb);
        gg.sync();
        if (it < 2) {
            for (int u = bid; u < 128; u += G) do_fprep(p, u, tid, (float*)eb);
            gg.sync();
        }
    }
    for (int u = bid; u < 768; u += G) do_final(p, u, tid);
}

// ===========================================================================
// Fallback standalone kernels (one phase each)
// ===========================================================================
__global__ __launch_bounds__(256) void k_pre(Params p) {
    __shared__ __align__(16) short eb[4352];   // 32*33 floats
    do_pre(p, blockIdx.x, threadIdx.x, eb);
}
__global__ __launch_bounds__(256) void k_gemm(Params p) {
    __shared__ __align__(16) short eb[128 * 128];
    do_gemm(p, blockIdx.x, threadIdx.x, eb);
}
__global__ __launch_bounds__(256) void k_fprep0(Params p) {
    __shared__ float red[512];
    do_fprep0(p, blockIdx.x, threadIdx.x, red);
}
__global__ __launch_bounds__(256) void k_gll(Params p) {
    __shared__ __align__(16) short eb[192 * 16];  // 3 KB f32x4[192]
    do_gll(p, blockIdx.x, threadIdx.x, eb);
}
__global__ __launch_bounds__(256) void k_musigma(Params p) {
    __shared__ float asml[512];
    do_musigma(p, blockIdx.x, threadIdx.x, asml);
}
__global__ __launch_bounds__(256) void k_fprep(Params p) {
    __shared__ float red[512];
    do_fprep(p, blockIdx.x, threadIdx.x, red);
}
__global__ __launch_bounds__(256) void k_final(Params p) {
    do_final(p, blockIdx.x, threadIdx.x);
}

// ===========================================================================
extern "C" void kernel_launch(void* const* d_in, const int* in_sizes, int n_in,
                              void* d_out, int out_size, void* d_ws, size_t ws_size,
                              hipStream_t stream)
{
    Params pp;
    pp.emb         = (const float*)d_in[0];
    pp.noise_init  = (const float*)d_in[1];
    pp.noise_final = (const float*)d_in[2];
    pp.slots_mu    = (const float*)d_in[3];
    pp.slots_logsg = (const float*)d_in[4];
    pp.mixing_co   = (const float*)d_in[5];
    pp.Wk          = (const float*)d_in[6];
    pp.bk          = (const float*)d_in[7];
    pp.Wq          = (const float*)d_in[8];
    pp.bq          = (const float*)d_in[9];
    pp.Wv          = (const float*)d_in[10];
    pp.bv          = (const float*)d_in[11];
    pp.ln_g        = (const float*)d_in[12];
    pp.ln_b        = (const float*)d_in[13];
    pp.out         = (float*)d_out;

    float* ws = (float*)d_ws;
    pp.queries = ws;
    pp.attn    = pp.queries + BB * KK * DD;
    pp.s1p     = pp.attn + BB * NN * KK;
    pp.s2p     = pp.s1p + (size_t)BB * 16 * KK * DD;
    pp.off     = pp.s2p + (size_t)BB * 16 * KK * DD;
    pp.mix16   = pp.off + BB * 16;
    pp.colsum  = pp.mix16 + BB * 16;
    pp.Abf     = (short*)(pp.colsum + BB * KK);
    pp.E       = pp.Abf + (size_t)BB * NN * DD;
    pp.Vbf     = pp.E + (size_t)BB * NN * 1024;
    pp.WtKV    = pp.Vbf + (size_t)BB * NN * DD;
    pp.WqT     = pp.WtKV + (size_t)1024 * DD;
    pp.slotbf  = pp.WqT + (size_t)DD * DD;
    pp.F_bt    = pp.slotbf + (size_t)BB * KK * DD;

    void* args[] = { (void*)&pp };
    hipError_t e = hipLaunchCooperativeKernel((const void*)fused_kernel,
                                              dim3(512), dim3(256), args, 0, stream);
    if (e != hipSuccess)
        e = hipLaunchCooperativeKernel((const void*)fused_kernel,
                                       dim3(256), dim3(256), args, 0, stream);
    if (e != hipSuccess) {
        // Fallback: multi-kernel sequence (identical numerics).
        k_pre<<<4992, 256, 0, stream>>>(pp);
        k_gemm<<<1032, 256, 0, stream>>>(pp);
        k_fprep0<<<256, 256, 0, stream>>>(pp);
        for (int it = 0; it < 3; it++) {
            k_gll<<<1024, 256, 0, stream>>>(pp);
            k_musigma<<<256, 256, 0, stream>>>(pp);
            if (it < 2) k_fprep<<<128, 256, 0, stream>>>(pp);
        }
        k_final<<<768, 256, 0, stream>>>(pp);
    }
}

// Round 8
// 243.620 us; speedup vs baseline: 3.5589x; 3.5589x over previous
//
#include <hip/hip_runtime.h>
#include <math.h>

// Problem constants
#define BB 16
#define NN 1024
#define DD 512
#define KK 8
#define EPS_ 1e-8f
#define LN_EPS_ 1e-5f
// -0.5 * D * log(2*pi)
#define GLL_C0 (-470.4965290007924f)

typedef __attribute__((ext_vector_type(8))) short short8;
typedef __attribute__((ext_vector_type(4))) short short4v;
typedef __attribute__((ext_vector_type(4))) float f32x4;

static __device__ inline short f2bf(float f) {
    unsigned u = __builtin_bit_cast(unsigned, f);
    u = (u + 0x7fff + ((u >> 16) & 1)) >> 16;
    return (short)u;
}
static __device__ inline float bf2f(short s) {
    unsigned u = ((unsigned)(unsigned short)s) << 16;
    return __builtin_bit_cast(float, u);
}
static __device__ inline void gload16(const void* g, void* l) {
    __builtin_amdgcn_global_load_lds(
        (const __attribute__((address_space(1))) void*)g,
        (__attribute__((address_space(3))) void*)l, 16, 0, 0);
}

struct Params {
    const float *emb, *noise_init, *noise_final, *slots_mu, *slots_logsg,
                *mixing_co, *Wk, *bk, *Wq, *bq, *Wv, *bv, *ln_g, *ln_b;
    float *out;
    float *queries, *attn, *s1p, *s2p, *off, *mix16, *colsum;
    short *Abf, *E, *Vbf, *WtKV, *WqT, *slotbf, *F_bt;
};

// ===========================================================================
// 1) pre: u in [0,4992) : LN+cast | weight transpose | slot init
//    (verified correct in round 7)
// ===========================================================================
__global__ __launch_bounds__(256) void k_pre(Params p)
{
    __shared__ __align__(16) short eb[4352];
    int u = blockIdx.x, tid = threadIdx.x;
    if (u < 4096) {
        int row  = u * 4 + (tid >> 6);
        int lane = tid & 63;
        const float* e = p.emb + (size_t)row * DD + lane * 8;
        float4 v0 = *(const float4*)e;
        float4 v1 = *(const float4*)(e + 4);
        float v[8] = {v0.x, v0.y, v0.z, v0.w, v1.x, v1.y, v1.z, v1.w};
        float s = 0.0f;
#pragma unroll
        for (int j = 0; j < 8; j++) s += v[j];
#pragma unroll
        for (int off = 32; off; off >>= 1) s += __shfl_xor(s, off);
        float m = s * (1.0f / DD);
        float vs = 0.0f;
#pragma unroll
        for (int j = 0; j < 8; j++) { float d = v[j] - m; vs = fmaf(d, d, vs); }
#pragma unroll
        for (int off = 32; off; off >>= 1) vs += __shfl_xor(vs, off);
        float rstd = rsqrtf(vs * (1.0f / DD) + LN_EPS_);

        float4 g0 = *(const float4*)&p.ln_g[lane * 8];
        float4 g1 = *(const float4*)&p.ln_g[lane * 8 + 4];
        float4 b0 = *(const float4*)&p.ln_b[lane * 8];
        float4 b1 = *(const float4*)&p.ln_b[lane * 8 + 4];
        float g[8] = {g0.x, g0.y, g0.z, g0.w, g1.x, g1.y, g1.z, g1.w};
        float bb[8] = {b0.x, b0.y, b0.z, b0.w, b1.x, b1.y, b1.z, b1.w};
        short8 o;
#pragma unroll
        for (int j = 0; j < 8; j++) o[j] = f2bf(fmaf((v[j] - m) * rstd, g[j], bb[j]));
        *(short8*)&p.Abf[(size_t)row * DD + lane * 8] = o;
    } else if (u < 4864) {
        int idx = u - 4096;
        int z = idx >> 8, rem = idx & 255;
        const float* W = (z == 0) ? p.Wk : (z == 1) ? p.Wv : p.Wq;
        short* T; int nbase;
        if (z < 2) { T = p.WtKV; nbase = z * 512; } else { T = p.WqT; nbase = 0; }
        int k0 = (rem & 15) * 32, n0 = (rem >> 4) * 32;
        int tx = tid & 31, ty = tid >> 5;
        float (*t)[33] = (float (*)[33])eb;
#pragma unroll
        for (int q = 0; q < 4; q++)
            t[ty + q * 8][tx] = W[(size_t)(k0 + ty + q * 8) * DD + n0 + tx];
        __syncthreads();
#pragma unroll
        for (int q = 0; q < 4; q++)
            T[(size_t)(nbase + n0 + ty + q * 8) * DD + k0 + tx] = f2bf(t[tx][ty + q * 8]);
    } else {
        int idx = u - 4864;
        int b = idx >> 3, k = idx & 7;
#pragma unroll
        for (int q = 0; q < 2; q++) {
            int d = tid + q * 256;
            float sg = expf(p.slots_logsg[k * DD + d]);
            float sl = fmaf(sg, p.noise_init[((size_t)(b * KK + k)) * DD + d],
                            p.slots_mu[k * DD + d]);
            p.slotbf[((size_t)(b * KK + k)) * DD + d] = f2bf(sl);
        }
    }
}

// ===========================================================================
// 2) gemm: u in [0,1032) : 128x128 MFMA GEMM, LDS-coalesced epilogue
//    (verified correct in round 7)
// ===========================================================================
__global__ __launch_bounds__(256) void k_gemm(Params p)
{
    __shared__ __align__(16) short eb[128 * 128];
    int u = blockIdx.x, tid = threadIdx.x;
    int w = tid >> 6, l = tid & 63;
    int x = u & 7, by = u >> 3;
    int qmode = (by == 128);
    if (qmode && x >= 4) return;
    const short* A  = qmode ? p.slotbf : p.Abf + (size_t)by * 128 * DD;
    const short* Bt = qmode ? p.WqT : p.WtKV;
    int row0 = qmode ? 0 : by * 128;
    int col0 = x * 128;

    short* As = eb;
    short* Bs = eb + 8192;
    int sr = l >> 3;
    int sg_off = ((l & 7) ^ sr) * 8;
    int mq = (w & 1) * 64, nq = (w >> 1) * 64;
    int fr = l & 15;
    int orow = (l >> 4) * 4, ocol = l & 15;

    f32x4 acc[4][4] = {};
    for (int k0 = 0; k0 < DD; k0 += 64) {
        __syncthreads();
#pragma unroll
        for (int j = 0; j < 4; j++) {
            int rb = w * 32 + j * 8;
            int r  = rb + sr;
            gload16(A  + (size_t)r * DD + k0 + sg_off, &As[rb * 64 + l * 8]);
            gload16(Bt + (size_t)(col0 + r) * DD + k0 + sg_off, &Bs[rb * 64 + l * 8]);
        }
        __syncthreads();
#pragma unroll
        for (int kk = 0; kk < 2; kk++) {
            int g = kk * 4 + (l >> 4);
            short8 af[4], bfv[4];
#pragma unroll
            for (int mi = 0; mi < 4; mi++)
                af[mi] = *(const short8*)&As[(mq + mi * 16 + fr) * 64 + (g ^ (fr & 7)) * 8];
#pragma unroll
            for (int ni = 0; ni < 4; ni++)
                bfv[ni] = *(const short8*)&Bs[(nq + ni * 16 + fr) * 64 + (g ^ (fr & 7)) * 8];
#pragma unroll
            for (int mi = 0; mi < 4; mi++)
#pragma unroll
                for (int ni = 0; ni < 4; ni++)
                    acc[mi][ni] = __builtin_amdgcn_mfma_f32_16x16x32_bf16(
                        af[mi], bfv[ni], acc[mi][ni], 0, 0, 0);
        }
    }

    float bvv[4];
#pragma unroll
    for (int ni = 0; ni < 4; ni++) {
        int col = col0 + nq + ni * 16 + ocol;
        bvv[ni] = qmode ? p.bq[col] : (x < 4 ? p.bk[col] : p.bv[col - 512]);
    }

    __syncthreads();
    if (qmode) {
#pragma unroll
        for (int ni = 0; ni < 4; ni++) {
            int col = col0 + nq + ni * 16 + ocol;
#pragma unroll
            for (int mi = 0; mi < 4; mi++)
#pragma unroll
                for (int r = 0; r < 4; r++)
                    p.queries[(size_t)(mq + mi * 16 + orow + r) * DD + col] =
                        acc[mi][ni][r] + bvv[ni];
        }
    } else {
        int npass = (x < 4) ? 2 : 1;
        for (int pass = 0; pass < npass; pass++) {
#pragma unroll
            for (int mi = 0; mi < 4; mi++)
#pragma unroll
                for (int r = 0; r < 4; r++) {
                    int row = mq + mi * 16 + orow + r;
                    int sw = ((row >> 2) & 3) << 1;
#pragma unroll
                    for (int ni = 0; ni < 4; ni++) {
                        int colg = nq + ni * 16 + ocol;
                        float val = acc[mi][ni][r] + bvv[ni];
                        if (x < 4 && pass == 0) val = val * val;
                        eb[row * 128 + (((colg >> 3) ^ sw) * 8) + (colg & 7)] = f2bf(val);
                    }
                }
            __syncthreads();
#pragma unroll
            for (int i = 0; i < 8; i++) {
                int row = i * 16 + w * 4 + (l >> 4);
                int c = l & 15;
                int cc = c ^ (((row >> 2) & 3) << 1);
                short8 vv = *(const short8*)&eb[row * 128 + cc * 8];
                if (x < 4) {
                    size_t a = (size_t)(row0 + row) * 1024 +
                               (pass ? 512 + col0 : col0) + c * 8;
                    *(short8*)&p.E[a] = vv;
                } else {
                    *(short8*)&p.Vbf[(size_t)(row0 + row) * 512 +
                                     (col0 - 512) + c * 8] = vv;
                }
            }
            __syncthreads();
        }
    }
}

// ===========================================================================
// 3) fprep0: u in [0,256)  (verified correct in round 7)
// ===========================================================================
__global__ __launch_bounds__(256) void k_fprep0(Params p)
{
    __shared__ float red[512];
    int u = blockIdx.x, tid = threadIdx.x;
    int b = u >> 4, k = u & 15;
    short* Fr = p.F_bt + (size_t)(b * 16 + k) * 1024;
    if (k >= KK) {
        short4v zv = {0, 0, 0, 0};
        *(short4v*)&Fr[tid * 4] = zv;
        if (tid == 0) { p.off[b * 16 + k] = 0.0f; p.mix16[b * 16 + k] = 0.0f; }
        return;
    }
    float* rc = red;
    float* rl = red + 256;
    float c = 0.0f, ld = 0.0f;
#pragma unroll
    for (int q = 0; q < 2; q++) {
        int d = tid * 2 + q;
        float sg = expf(p.slots_logsg[k * DD + d]);
        float iv = 1.0f / (sg * sg + EPS_);
        float qv = p.queries[((size_t)(b * KK + k)) * DD + d];
        Fr[d]       = f2bf(-0.5f * iv);
        Fr[512 + d] = f2bf(qv * iv);
        c  = fmaf(qv * qv, iv, c);
        ld += logf(fabsf(sg) + EPS_);
    }
    rc[tid] = c; rl[tid] = ld;
    __syncthreads();
    for (int s = 128; s > 0; s >>= 1) {
        if (tid < s) { rc[tid] += rc[tid + s]; rl[tid] += rl[tid + s]; }
        __syncthreads();
    }
    if (tid == 0) {
        p.off[b * 16 + k]    = GLL_C0 - 0.5f * rl[0] - 0.5f * rc[0];
        p.mix16[b * 16 + k]  = p.mixing_co[k];
        p.colsum[b * KK + k] = 0.0f;
    }
}

// ===========================================================================
// 4) FUSED gll + musigma: grid (256) = (b, chunk of 64 rows).
//    Phase A: 4 waves, each one 16-row M-tile, full K=1024 (32 MFMAs);
//    normalize; attn -> LDS + global; colsum atomics.
//    Phase B: s1/s2 partial sums over the same 64 rows, attn from LDS.
// ===========================================================================
__global__ __launch_bounds__(256) void k_gllmu(Params p)
{
    __shared__ float asml[64 * KK];   // attn for this chunk
    int u = blockIdx.x, tid = threadIdx.x;
    int w = tid >> 6, l = tid & 63;
    int b = u >> 4, chunk = u & 15;
    int n0 = chunk * 64;
    int m0 = n0 + w * 16;

    // ---- phase A: gll MFMA ----
    const short* Ea = p.E + ((size_t)(b * NN + m0 + (l & 15))) * 1024 + (l >> 4) * 8;
    const short* Fa = p.F_bt + (size_t)(b * 16 + (l & 15)) * 1024 + (l >> 4) * 8;
    f32x4 acc = {};
#pragma unroll 8
    for (int j = 0; j < 32; j++) {
        short8 af = *(const short8*)&Ea[j * 32];
        short8 bf = *(const short8*)&Fa[j * 32];
        acc = __builtin_amdgcn_mfma_f32_16x16x32_bf16(af, bf, acc, 0, 0, 0);
    }
    int col = l & 15;
    int rloc = w * 16 + (l >> 4) * 4;     // row within 64-row chunk
    float offv = p.off[b * 16 + col];
    float mixv = p.mix16[b * 16 + col];
    float a[4], den[4];
#pragma unroll
    for (int r = 0; r < 4; r++) {
        a[r] = mixv * (acc[r] + offv);
        den[r] = a[r];
    }
#pragma unroll
    for (int mask = 1; mask <= 8; mask <<= 1)
#pragma unroll
        for (int r = 0; r < 4; r++) den[r] += __shfl_xor(den[r], mask);
    float csl = 0.0f;
    if (col < KK) {
#pragma unroll
        for (int r = 0; r < 4; r++) {
            float vv = a[r] / den[r];
            asml[(rloc + r) * KK + col] = vv;
            p.attn[((size_t)(b * NN + n0 + rloc + r)) * KK + col] = vv;
            csl += vv;
        }
    }
    csl += __shfl_xor(csl, 16);
    csl += __shfl_xor(csl, 32);
    if (l < KK) atomicAdd(&p.colsum[b * KK + l], csl);

    __syncthreads();

    // ---- phase B: musigma partial sums ----
    int d0 = tid * 2;
    float s1[2][KK] = {}, s2[2][KK] = {};
    const short* vb = p.Vbf + ((size_t)(b * NN + n0)) * DD + d0;
#pragma unroll 4
    for (int nn = 0; nn < 64; nn++) {
        short2 vs = *(const short2*)&vb[(size_t)nn * DD];
        float v0 = bf2f(vs.x), v1 = bf2f(vs.y);
        float v0q = v0 * v0, v1q = v1 * v1;
        float4 a0 = *(const float4*)&asml[nn * KK];
        float4 a1 = *(const float4*)&asml[nn * KK + 4];
        float aa[8] = {a0.x, a0.y, a0.z, a0.w, a1.x, a1.y, a1.z, a1.w};
#pragma unroll
        for (int k = 0; k < KK; k++) {
            s1[0][k] = fmaf(aa[k], v0, s1[0][k]);
            s2[0][k] = fmaf(aa[k], v0q, s2[0][k]);
            s1[1][k] = fmaf(aa[k], v1, s1[1][k]);
            s2[1][k] = fmaf(aa[k], v1q, s2[1][k]);
        }
    }
    size_t base = ((size_t)(b * 16 + chunk) * KK) * DD + d0;
#pragma unroll
    for (int k = 0; k < KK; k++) {
        *(float2*)&p.s1p[base + (size_t)k * DD] = make_float2(s1[0][k], s1[1][k]);
        *(float2*)&p.s2p[base + (size_t)k * DD] = make_float2(s2[0][k], s2[1][k]);
    }
}

// ===========================================================================
// 5) fprep: u in [0,128)  (verified correct in round 7)
// ===========================================================================
__global__ __launch_bounds__(256) void k_fprep(Params p)
{
    __shared__ float red[512];
    int u = blockIdx.x, tid = threadIdx.x;
    int b = u >> 3, k = u & 7;
    float cs   = p.colsum[b * KK + k];
    float inv  = 1.0f / (cs + EPS_);
    float ssum = cs * inv;
    short* Fr = p.F_bt + (size_t)(b * 16 + k) * 1024;
    float* rc = red;
    float* rl = red + 256;
    float c = 0.0f, ld = 0.0f;
#pragma unroll
    for (int q = 0; q < 2; q++) {
        int d = tid * 2 + q;
        float s1 = 0.0f, s2 = 0.0f;
#pragma unroll
        for (int ns = 0; ns < 16; ns++) {
            size_t o = ((size_t)(b * 16 + ns) * KK + k) * DD + d;
            s1 += p.s1p[o];
            s2 += p.s2p[o];
        }
        float m  = s1 * inv;
        float sg = s2 * inv - m * m * (2.0f - ssum);
        float iv = 1.0f / (sg * sg + EPS_);
        float qv = p.queries[((size_t)(b * KK + k)) * DD + d];
        Fr[d]       = f2bf(-0.5f * iv);
        Fr[512 + d] = f2bf(qv * iv);
        c  = fmaf(qv * qv, iv, c);
        ld += logf(fabsf(sg) + EPS_);
    }
    rc[tid] = c; rl[tid] = ld;
    __syncthreads();
    for (int s = 128; s > 0; s >>= 1) {
        if (tid < s) { rc[tid] += rc[tid + s]; rl[tid] += rl[tid + s]; }
        __syncthreads();
    }
    if (tid == 0) {
        p.off[b * 16 + k]    = GLL_C0 - 0.5f * rl[0] - 0.5f * rc[0];
        p.mix16[b * 16 + k]  = ssum * (1.0f / NN);
        p.colsum[b * KK + k] = 0.0f;
    }
}

// ===========================================================================
// 6) final: u in [0,768)  (verified correct in round 7)
// ===========================================================================
__global__ __launch_bounds__(256) void k_final(Params p)
{
    int u = blockIdx.x, tid = threadIdx.x;
    if (u < 256) {
        int gid = u * 256 + tid;
        int d = gid & 511;
        int k = (gid >> 9) & 7;
        int b = gid >> 12;
        float s1 = 0.0f, s2 = 0.0f;
#pragma unroll
        for (int ns = 0; ns < 16; ns++) {
            size_t o = ((size_t)(b * 16 + ns) * KK + k) * DD + d;
            s1 += p.s1p[o];
            s2 += p.s2p[o];
        }
        float cs   = p.colsum[b * KK + k];
        float inv  = 1.0f / (cs + EPS_);
        float ssum = cs * inv;
        float m    = s1 * inv;
        float sg   = s2 * inv - m * m * (2.0f - ssum);
        p.out[gid] = fmaf(fmaxf(fabsf(sg), EPS_), p.noise_final[gid], m);
    } else {
        int gid = (u - 256) * 256 + tid;
        int b = gid >> 13;
        int k = (gid >> 10) & 7;
        int n = gid & 1023;
        float cs = p.colsum[b * KK + k];
        p.out[BB * KK * DD + gid] =
            p.attn[((size_t)(b * NN + n)) * KK + k] / (cs + EPS_);
    }
}

// ===========================================================================
extern "C" void kernel_launch(void* const* d_in, const int* in_sizes, int n_in,
                              void* d_out, int out_size, void* d_ws, size_t ws_size,
                              hipStream_t stream)
{
    Params pp;
    pp.emb         = (const float*)d_in[0];
    pp.noise_init  = (const float*)d_in[1];
    pp.noise_final = (const float*)d_in[2];
    pp.slots_mu    = (const float*)d_in[3];
    pp.slots_logsg = (const float*)d_in[4];
    pp.mixing_co   = (const float*)d_in[5];
    pp.Wk          = (const float*)d_in[6];
    pp.bk          = (const float*)d_in[7];
    pp.Wq          = (const float*)d_in[8];
    pp.bq          = (const float*)d_in[9];
    pp.Wv          = (const float*)d_in[10];
    pp.bv          = (const float*)d_in[11];
    pp.ln_g        = (const float*)d_in[12];
    pp.ln_b        = (const float*)d_in[13];
    pp.out         = (float*)d_out;

    float* ws = (float*)d_ws;
    pp.queries = ws;
    pp.attn    = pp.queries + BB * KK * DD;
    pp.s1p     = pp.attn + BB * NN * KK;
    pp.s2p     = pp.s1p + (size_t)BB * 16 * KK * DD;
    pp.off     = pp.s2p + (size_t)BB * 16 * KK * DD;
    pp.mix16   = pp.off + BB * 16;
    pp.colsum  = pp.mix16 + BB * 16;
    pp.Abf     = (short*)(pp.colsum + BB * KK);
    pp.E       = pp.Abf + (size_t)BB * NN * DD;
    pp.Vbf     = pp.E + (size_t)BB * NN * 1024;
    pp.WtKV    = pp.Vbf + (size_t)BB * NN * DD;
    pp.WqT     = pp.WtKV + (size_t)1024 * DD;
    pp.slotbf  = pp.WqT + (size_t)DD * DD;
    pp.F_bt    = pp.slotbf + (size_t)BB * KK * DD;

    k_pre<<<4992, 256, 0, stream>>>(pp);
    k_gemm<<<1032, 256, 0, stream>>>(pp);
    k_fprep0<<<256, 256, 0, stream>>>(pp);
    for (int it = 0; it < 3; it++) {
        k_gllmu<<<256, 256, 0, stream>>>(pp);
        if (it < 2) k_fprep<<<128, 256, 0, stream>>>(pp);
    }
    k_final<<<768, 256, 0, stream>>>(pp);
}

// Round 9
// 219.075 us; speedup vs baseline: 3.9576x; 1.1120x over previous
//
#include <hip/hip_runtime.h>
#include <math.h>

// Problem constants
#define BB 16
#define NN 1024
#define DD 512
#define KK 8
#define EPS_ 1e-8f
#define LN_EPS_ 1e-5f
// -0.5 * D * log(2*pi)
#define GLL_C0 (-470.4965290007924f)

typedef __attribute__((ext_vector_type(8))) short short8;
typedef __attribute__((ext_vector_type(4))) short short4v;
typedef __attribute__((ext_vector_type(4))) float f32x4;

static __device__ inline short f2bf(float f) {
    unsigned u = __builtin_bit_cast(unsigned, f);
    u = (u + 0x7fff + ((u >> 16) & 1)) >> 16;
    return (short)u;
}
static __device__ inline float bf2f(short s) {
    unsigned u = ((unsigned)(unsigned short)s) << 16;
    return __builtin_bit_cast(float, u);
}
static __device__ inline void gload16(const void* g, void* l) {
    __builtin_amdgcn_global_load_lds(
        (const __attribute__((address_space(1))) void*)g,
        (__attribute__((address_space(3))) void*)l, 16, 0, 0);
}

struct Params {
    const float *emb, *noise_init, *noise_final, *slots_mu, *slots_logsg,
                *mixing_co, *Wk, *bk, *Wq, *bq, *Wv, *bv, *ln_g, *ln_b;
    float *out;
    float *queries, *attn, *s1p, *s2p, *off, *mix16, *colsum;
    short *Abf, *E, *Vbf, *WtKV, *WqT, *slotbf, *F_bt;
};

// ===========================================================================
// 1) pre: u in [0,4992) : LN+cast | weight transpose | slot init
//    (verified correct rounds 7-8)
// ===========================================================================
__global__ __launch_bounds__(256) void k_pre(Params p)
{
    __shared__ __align__(16) short eb[4352];
    int u = blockIdx.x, tid = threadIdx.x;
    if (u < 4096) {
        int row  = u * 4 + (tid >> 6);
        int lane = tid & 63;
        const float* e = p.emb + (size_t)row * DD + lane * 8;
        float4 v0 = *(const float4*)e;
        float4 v1 = *(const float4*)(e + 4);
        float v[8] = {v0.x, v0.y, v0.z, v0.w, v1.x, v1.y, v1.z, v1.w};
        float s = 0.0f;
#pragma unroll
        for (int j = 0; j < 8; j++) s += v[j];
#pragma unroll
        for (int off = 32; off; off >>= 1) s += __shfl_xor(s, off);
        float m = s * (1.0f / DD);
        float vs = 0.0f;
#pragma unroll
        for (int j = 0; j < 8; j++) { float d = v[j] - m; vs = fmaf(d, d, vs); }
#pragma unroll
        for (int off = 32; off; off >>= 1) vs += __shfl_xor(vs, off);
        float rstd = rsqrtf(vs * (1.0f / DD) + LN_EPS_);

        float4 g0 = *(const float4*)&p.ln_g[lane * 8];
        float4 g1 = *(const float4*)&p.ln_g[lane * 8 + 4];
        float4 b0 = *(const float4*)&p.ln_b[lane * 8];
        float4 b1 = *(const float4*)&p.ln_b[lane * 8 + 4];
        float g[8] = {g0.x, g0.y, g0.z, g0.w, g1.x, g1.y, g1.z, g1.w};
        float bb[8] = {b0.x, b0.y, b0.z, b0.w, b1.x, b1.y, b1.z, b1.w};
        short8 o;
#pragma unroll
        for (int j = 0; j < 8; j++) o[j] = f2bf(fmaf((v[j] - m) * rstd, g[j], bb[j]));
        *(short8*)&p.Abf[(size_t)row * DD + lane * 8] = o;
    } else if (u < 4864) {
        int idx = u - 4096;
        int z = idx >> 8, rem = idx & 255;
        const float* W = (z == 0) ? p.Wk : (z == 1) ? p.Wv : p.Wq;
        short* T; int nbase;
        if (z < 2) { T = p.WtKV; nbase = z * 512; } else { T = p.WqT; nbase = 0; }
        int k0 = (rem & 15) * 32, n0 = (rem >> 4) * 32;
        int tx = tid & 31, ty = tid >> 5;
        float (*t)[33] = (float (*)[33])eb;
#pragma unroll
        for (int q = 0; q < 4; q++)
            t[ty + q * 8][tx] = W[(size_t)(k0 + ty + q * 8) * DD + n0 + tx];
        __syncthreads();
#pragma unroll
        for (int q = 0; q < 4; q++)
            T[(size_t)(nbase + n0 + ty + q * 8) * DD + k0 + tx] = f2bf(t[tx][ty + q * 8]);
    } else {
        int idx = u - 4864;
        int b = idx >> 3, k = idx & 7;
#pragma unroll
        for (int q = 0; q < 2; q++) {
            int d = tid + q * 256;
            float sg = expf(p.slots_logsg[k * DD + d]);
            float sl = fmaf(sg, p.noise_init[((size_t)(b * KK + k)) * DD + d],
                            p.slots_mu[k * DD + d]);
            p.slotbf[((size_t)(b * KK + k)) * DD + d] = f2bf(sl);
        }
    }
}

// ===========================================================================
// 2) gemm: u in [0,1032) : 128x128 MFMA GEMM, LDS DOUBLE-BUFFERED staging
//    (1 barrier per K-iteration; stage k+1 overlaps compute k),
//    LDS-coalesced epilogue (verified round 7-8).
// ===========================================================================
__global__ __launch_bounds__(256) void k_gemm(Params p)
{
    // [0..8191]=As0 [8192..16383]=As1 [16384..24575]=Bs0 [24576..32767]=Bs1
    __shared__ __align__(16) short smem[32768];   // 64 KB
    int u = blockIdx.x, tid = threadIdx.x;
    int w = tid >> 6, l = tid & 63;
    int x = u & 7, by = u >> 3;
    int qmode = (by == 128);
    if (qmode && x >= 4) return;
    const short* A  = qmode ? p.slotbf : p.Abf + (size_t)by * 128 * DD;
    const short* Bt = qmode ? p.WqT : p.WtKV;
    int row0 = qmode ? 0 : by * 128;
    int col0 = x * 128;

    int sr = l >> 3;
    int sg_off = ((l & 7) ^ sr) * 8;
    int mq = (w & 1) * 64, nq = (w >> 1) * 64;
    int fr = l & 15;
    int orow = (l >> 4) * 4, ocol = l & 15;

    // stage K-tile k0 into buffer buf
#define STAGE(buf, k0)                                                        \
    {                                                                         \
        short* As_ = smem + (buf) * 8192;                                     \
        short* Bs_ = smem + 16384 + (buf) * 8192;                             \
        _Pragma("unroll")                                                     \
        for (int j = 0; j < 4; j++) {                                         \
            int rb = w * 32 + j * 8;                                          \
            int r  = rb + sr;                                                 \
            gload16(A  + (size_t)r * DD + (k0) + sg_off, &As_[rb * 64 + l * 8]);   \
            gload16(Bt + (size_t)(col0 + r) * DD + (k0) + sg_off, &Bs_[rb * 64 + l * 8]); \
        }                                                                     \
    }

    f32x4 acc[4][4] = {};
    STAGE(0, 0);
    __syncthreads();
    for (int i = 0; i < 8; i++) {
        if (i < 7) STAGE((i + 1) & 1, (i + 1) * 64);
        const short* As_ = smem + (i & 1) * 8192;
        const short* Bs_ = smem + 16384 + (i & 1) * 8192;
#pragma unroll
        for (int kk = 0; kk < 2; kk++) {
            int g = kk * 4 + (l >> 4);
            short8 af[4], bfv[4];
#pragma unroll
            for (int mi = 0; mi < 4; mi++)
                af[mi] = *(const short8*)&As_[(mq + mi * 16 + fr) * 64 + (g ^ (fr & 7)) * 8];
#pragma unroll
            for (int ni = 0; ni < 4; ni++)
                bfv[ni] = *(const short8*)&Bs_[(nq + ni * 16 + fr) * 64 + (g ^ (fr & 7)) * 8];
#pragma unroll
            for (int mi = 0; mi < 4; mi++)
#pragma unroll
                for (int ni = 0; ni < 4; ni++)
                    acc[mi][ni] = __builtin_amdgcn_mfma_f32_16x16x32_bf16(
                        af[mi], bfv[ni], acc[mi][ni], 0, 0, 0);
        }
        __syncthreads();
    }
#undef STAGE

    float bvv[4];
#pragma unroll
    for (int ni = 0; ni < 4; ni++) {
        int col = col0 + nq + ni * 16 + ocol;
        bvv[ni] = qmode ? p.bq[col] : (x < 4 ? p.bk[col] : p.bv[col - 512]);
    }

    if (qmode) {
#pragma unroll
        for (int ni = 0; ni < 4; ni++) {
            int col = col0 + nq + ni * 16 + ocol;
#pragma unroll
            for (int mi = 0; mi < 4; mi++)
#pragma unroll
                for (int r = 0; r < 4; r++)
                    p.queries[(size_t)(mq + mi * 16 + orow + r) * DD + col] =
                        acc[mi][ni][r] + bvv[ni];
        }
    } else {
        short* eb = smem;   // 32 KB epilogue buffer (As region + As1)
        int npass = (x < 4) ? 2 : 1;
        for (int pass = 0; pass < npass; pass++) {
#pragma unroll
            for (int mi = 0; mi < 4; mi++)
#pragma unroll
                for (int r = 0; r < 4; r++) {
                    int row = mq + mi * 16 + orow + r;
                    int sw = ((row >> 2) & 3) << 1;
#pragma unroll
                    for (int ni = 0; ni < 4; ni++) {
                        int colg = nq + ni * 16 + ocol;
                        float val = acc[mi][ni][r] + bvv[ni];
                        if (x < 4 && pass == 0) val = val * val;
                        eb[row * 128 + (((colg >> 3) ^ sw) * 8) + (colg & 7)] = f2bf(val);
                    }
                }
            __syncthreads();
#pragma unroll
            for (int i = 0; i < 8; i++) {
                int row = i * 16 + w * 4 + (l >> 4);
                int c = l & 15;
                int cc = c ^ (((row >> 2) & 3) << 1);
                short8 vv = *(const short8*)&eb[row * 128 + cc * 8];
                if (x < 4) {
                    size_t a = (size_t)(row0 + row) * 1024 +
                               (pass ? 512 + col0 : col0) + c * 8;
                    *(short8*)&p.E[a] = vv;
                } else {
                    *(short8*)&p.Vbf[(size_t)(row0 + row) * 512 +
                                     (col0 - 512) + c * 8] = vv;
                }
            }
            __syncthreads();
        }
    }
}

// ===========================================================================
// 3) fprep0: u in [0,256)  (verified rounds 7-8)
// ===========================================================================
__global__ __launch_bounds__(256) void k_fprep0(Params p)
{
    __shared__ float red[512];
    int u = blockIdx.x, tid = threadIdx.x;
    int b = u >> 4, k = u & 15;
    short* Fr = p.F_bt + (size_t)(b * 16 + k) * 1024;
    if (k >= KK) {
        short4v zv = {0, 0, 0, 0};
        *(short4v*)&Fr[tid * 4] = zv;
        if (tid == 0) { p.off[b * 16 + k] = 0.0f; p.mix16[b * 16 + k] = 0.0f; }
        return;
    }
    float* rc = red;
    float* rl = red + 256;
    float c = 0.0f, ld = 0.0f;
#pragma unroll
    for (int q = 0; q < 2; q++) {
        int d = tid * 2 + q;
        float sg = expf(p.slots_logsg[k * DD + d]);
        float iv = 1.0f / (sg * sg + EPS_);
        float qv = p.queries[((size_t)(b * KK + k)) * DD + d];
        Fr[d]       = f2bf(-0.5f * iv);
        Fr[512 + d] = f2bf(qv * iv);
        c  = fmaf(qv * qv, iv, c);
        ld += logf(fabsf(sg) + EPS_);
    }
    rc[tid] = c; rl[tid] = ld;
    __syncthreads();
    for (int s = 128; s > 0; s >>= 1) {
        if (tid < s) { rc[tid] += rc[tid + s]; rl[tid] += rl[tid + s]; }
        __syncthreads();
    }
    if (tid == 0) {
        p.off[b * 16 + k]    = GLL_C0 - 0.5f * rl[0] - 0.5f * rc[0];
        p.mix16[b * 16 + k]  = p.mixing_co[k];
        p.colsum[b * KK + k] = 0.0f;
    }
}

// ===========================================================================
// 4) FUSED gll + musigma, 32-row chunks: grid (512) = (b, chunk).
//    Phase A: 4 waves = 2 row-tiles x 2 K-halves (split-K, LDS reduce),
//    2 accumulator chains per wave (8-deep).  Normalize; attn->LDS+global;
//    colsum atomics.  Phase B: s1/s2 partials over the 32 rows.
// ===========================================================================
__global__ __launch_bounds__(256) void k_gllmu(Params p)
{
    __shared__ f32x4 red[2][64];      // 2 KB: K-half reduction
    __shared__ float asml[32 * KK];   // 1 KB: attn for this chunk
    int u = blockIdx.x, tid = threadIdx.x;
    int w = tid >> 6, l = tid & 63;
    int b = u >> 5, chunk = u & 31;
    int n0 = chunk * 32;
    int t = w & 1, khalf = w >> 1;

    // ---- phase A: gll MFMA (split-K x2, 2 chains) ----
    const short* Ea = p.E + ((size_t)(b * NN + n0 + t * 16 + (l & 15))) * 1024
                      + khalf * 512 + (l >> 4) * 8;
    const short* Fa = p.F_bt + (size_t)(b * 16 + (l & 15)) * 1024
                      + khalf * 512 + (l >> 4) * 8;
    f32x4 acc0 = {}, acc1 = {};
#pragma unroll
    for (int j = 0; j < 8; j++) {
        short8 a0 = *(const short8*)&Ea[j * 64];
        short8 f0 = *(const short8*)&Fa[j * 64];
        acc0 = __builtin_amdgcn_mfma_f32_16x16x32_bf16(a0, f0, acc0, 0, 0, 0);
        short8 a1 = *(const short8*)&Ea[j * 64 + 32];
        short8 f1 = *(const short8*)&Fa[j * 64 + 32];
        acc1 = __builtin_amdgcn_mfma_f32_16x16x32_bf16(a1, f1, acc1, 0, 0, 0);
    }
    f32x4 acc = acc0 + acc1;

    if (khalf) red[t][l] = acc;
    __syncthreads();
    if (!khalf) {
        acc += red[t][l];
        int col = l & 15;
        int rloc = t * 16 + (l >> 4) * 4;      // row within 32-row chunk
        float offv = p.off[b * 16 + col];
        float mixv = p.mix16[b * 16 + col];
        float a[4], den[4];
#pragma unroll
        for (int r = 0; r < 4; r++) {
            a[r] = mixv * (acc[r] + offv);
            den[r] = a[r];
        }
#pragma unroll
        for (int mask = 1; mask <= 8; mask <<= 1)
#pragma unroll
            for (int r = 0; r < 4; r++) den[r] += __shfl_xor(den[r], mask);
        float csl = 0.0f;
        if (col < KK) {
#pragma unroll
            for (int r = 0; r < 4; r++) {
                float vv = a[r] / den[r];
                asml[(rloc + r) * KK + col] = vv;
                p.attn[((size_t)(b * NN + n0 + rloc + r)) * KK + col] = vv;
                csl += vv;
            }
        }
        csl += __shfl_xor(csl, 16);
        csl += __shfl_xor(csl, 32);
        if (l < KK) atomicAdd(&p.colsum[b * KK + l], csl);
    }
    __syncthreads();

    // ---- phase B: musigma partial sums over 32 rows ----
    int d0 = tid * 2;
    float s1[2][KK] = {}, s2[2][KK] = {};
    const short* vb = p.Vbf + ((size_t)(b * NN + n0)) * DD + d0;
#pragma unroll 4
    for (int nn = 0; nn < 32; nn++) {
        short2 vs = *(const short2*)&vb[(size_t)nn * DD];
        float v0 = bf2f(vs.x), v1 = bf2f(vs.y);
        float v0q = v0 * v0, v1q = v1 * v1;
        float4 a0 = *(const float4*)&asml[nn * KK];
        float4 a1 = *(const float4*)&asml[nn * KK + 4];
        float aa[8] = {a0.x, a0.y, a0.z, a0.w, a1.x, a1.y, a1.z, a1.w};
#pragma unroll
        for (int k = 0; k < KK; k++) {
            s1[0][k] = fmaf(aa[k], v0, s1[0][k]);
            s2[0][k] = fmaf(aa[k], v0q, s2[0][k]);
            s1[1][k] = fmaf(aa[k], v1, s1[1][k]);
            s2[1][k] = fmaf(aa[k], v1q, s2[1][k]);
        }
    }
    size_t base = ((size_t)(b * 32 + chunk) * KK) * DD + d0;
#pragma unroll
    for (int k = 0; k < KK; k++) {
        *(float2*)&p.s1p[base + (size_t)k * DD] = make_float2(s1[0][k], s1[1][k]);
        *(float2*)&p.s2p[base + (size_t)k * DD] = make_float2(s2[0][k], s2[1][k]);
    }
}

// ===========================================================================
// 5) fprep: u in [0,128)  (32 partials per b now)
// ===========================================================================
__global__ __launch_bounds__(256) void k_fprep(Params p)
{
    __shared__ float red[512];
    int u = blockIdx.x, tid = threadIdx.x;
    int b = u >> 3, k = u & 7;
    float cs   = p.colsum[b * KK + k];
    float inv  = 1.0f / (cs + EPS_);
    float ssum = cs * inv;
    short* Fr = p.F_bt + (size_t)(b * 16 + k) * 1024;
    float* rc = red;
    float* rl = red + 256;
    float c = 0.0f, ld = 0.0f;
#pragma unroll
    for (int q = 0; q < 2; q++) {
        int d = tid * 2 + q;
        float s1 = 0.0f, s2 = 0.0f;
#pragma unroll
        for (int ns = 0; ns < 32; ns++) {
            size_t o = ((size_t)(b * 32 + ns) * KK + k) * DD + d;
            s1 += p.s1p[o];
            s2 += p.s2p[o];
        }
        float m  = s1 * inv;
        float sg = s2 * inv - m * m * (2.0f - ssum);
        float iv = 1.0f / (sg * sg + EPS_);
        float qv = p.queries[((size_t)(b * KK + k)) * DD + d];
        Fr[d]       = f2bf(-0.5f * iv);
        Fr[512 + d] = f2bf(qv * iv);
        c  = fmaf(qv * qv, iv, c);
        ld += logf(fabsf(sg) + EPS_);
    }
    rc[tid] = c; rl[tid] = ld;
    __syncthreads();
    for (int s = 128; s > 0; s >>= 1) {
        if (tid < s) { rc[tid] += rc[tid + s]; rl[tid] += rl[tid + s]; }
        __syncthreads();
    }
    if (tid == 0) {
        p.off[b * 16 + k]    = GLL_C0 - 0.5f * rl[0] - 0.5f * rc[0];
        p.mix16[b * 16 + k]  = ssum * (1.0f / NN);
        p.colsum[b * KK + k] = 0.0f;
    }
}

// ===========================================================================
// 6) final: u in [0,768)  (32 partials per b now)
// ===========================================================================
__global__ __launch_bounds__(256) void k_final(Params p)
{
    int u = blockIdx.x, tid = threadIdx.x;
    if (u < 256) {
        int gid = u * 256 + tid;
        int d = gid & 511;
        int k = (gid >> 9) & 7;
        int b = gid >> 12;
        float s1 = 0.0f, s2 = 0.0f;
#pragma unroll
        for (int ns = 0; ns < 32; ns++) {
            size_t o = ((size_t)(b * 32 + ns) * KK + k) * DD + d;
            s1 += p.s1p[o];
            s2 += p.s2p[o];
        }
        float cs   = p.colsum[b * KK + k];
        float inv  = 1.0f / (cs + EPS_);
        float ssum = cs * inv;
        float m    = s1 * inv;
        float sg   = s2 * inv - m * m * (2.0f - ssum);
        p.out[gid] = fmaf(fmaxf(fabsf(sg), EPS_), p.noise_final[gid], m);
    } else {
        int gid = (u - 256) * 256 + tid;
        int b = gid >> 13;
        int k = (gid >> 10) & 7;
        int n = gid & 1023;
        float cs = p.colsum[b * KK + k];
        p.out[BB * KK * DD + gid] =
            p.attn[((size_t)(b * NN + n)) * KK + k] / (cs + EPS_);
    }
}

// ===========================================================================
extern "C" void kernel_launch(void* const* d_in, const int* in_sizes, int n_in,
                              void* d_out, int out_size, void* d_ws, size_t ws_size,
                              hipStream_t stream)
{
    Params pp;
    pp.emb         = (const float*)d_in[0];
    pp.noise_init  = (const float*)d_in[1];
    pp.noise_final = (const float*)d_in[2];
    pp.slots_mu    = (const float*)d_in[3];
    pp.slots_logsg = (const float*)d_in[4];
    pp.mixing_co   = (const float*)d_in[5];
    pp.Wk          = (const float*)d_in[6];
    pp.bk          = (const float*)d_in[7];
    pp.Wq          = (const float*)d_in[8];
    pp.bq          = (const float*)d_in[9];
    pp.Wv          = (const float*)d_in[10];
    pp.bv          = (const float*)d_in[11];
    pp.ln_g        = (const float*)d_in[12];
    pp.ln_b        = (const float*)d_in[13];
    pp.out         = (float*)d_out;

    float* ws = (float*)d_ws;
    pp.queries = ws;
    pp.attn    = pp.queries + BB * KK * DD;
    pp.s1p     = pp.attn + BB * NN * KK;
    pp.s2p     = pp.s1p + (size_t)BB * 32 * KK * DD;
    pp.off     = pp.s2p + (size_t)BB * 32 * KK * DD;
    pp.mix16   = pp.off + BB * 16;
    pp.colsum  = pp.mix16 + BB * 16;
    pp.Abf     = (short*)(pp.colsum + BB * KK);
    pp.E       = pp.Abf + (size_t)BB * NN * DD;
    pp.Vbf     = pp.E + (size_t)BB * NN * 1024;
    pp.WtKV    = pp.Vbf + (size_t)BB * NN * DD;
    pp.WqT     = pp.WtKV + (size_t)1024 * DD;
    pp.slotbf  = pp.WqT + (size_t)DD * DD;
    pp.F_bt    = pp.slotbf + (size_t)BB * KK * DD;

    k_pre<<<4992, 256, 0, stream>>>(pp);
    k_gemm<<<1032, 256, 0, stream>>>(pp);
    k_fprep0<<<256, 256, 0, stream>>>(pp);
    for (int it = 0; it < 3; it++) {
        k_gllmu<<<512, 256, 0, stream>>>(pp);
        if (it < 2) k_fprep<<<128, 256, 0, stream>>>(pp);
    }
    k_final<<<768, 256, 0, stream>>>(pp);
}